// Round 7
// baseline (7038.046 us; speedup 1.0000x reference)
//
#include <hip/hip_runtime.h>
#include <math.h>

#define BATCH 16
#define HID   128
#define NX    128
#define NF    4
#define NT    64
#define MODES 96
#define OM    (5 * HID)     // 640 fused W rows (F + 4*G)
#define NWG   256
#define TPB   512
#define ZSZ   ((size_t)BATCH * NX * HID)
#define HFST  (MODES * 8)   // per-(b,c,sub) hf block: 96 m x 8 o

// ---------------------------------------------------------------------------
// Tables: C[m][x]=cos(2pi k_m x/128), S=sin, k_m=(80+m)%128; T2x[x][m]={c,s}
// ---------------------------------------------------------------------------
__global__ void k_tables(float* __restrict__ C, float* __restrict__ S,
                         float2* __restrict__ T2x) {
    int m = blockIdx.x, x = threadIdx.x;
    if (x < NX) {
        int k = (80 + m) % NX;
        float ang = (float)((k * x) & (NX - 1)) * (2.0f * (float)M_PI / (float)NX);
        float c = cosf(ang), s = sinf(ang);
        C[m * NX + x] = c;
        S[m * NX + x] = s;
        T2x[x * MODES + m] = make_float2(c, s);
    }
}

// ---------------------------------------------------------------------------
// dxi[t][b][x][n] = xi[b,n,x,t+1] - xi[b,n,x,t]
// ---------------------------------------------------------------------------
__global__ void k_dxi(const float* __restrict__ xi, float* __restrict__ dxi) {
    int idx = blockIdx.x * blockDim.x + threadIdx.x;
    const int total = (NT - 1) * BATCH * NX * NF;
    if (idx < total) {
        int n = idx & (NF - 1);
        int x = (idx >> 2) & (NX - 1);
        int b = (idx >> 9) & (BATCH - 1);
        int t = idx >> 13;
        const float* base = xi + (((size_t)b * NF + n) * NX + x) * NT;
        dxi[idx] = base[t + 1] - base[t];
    }
}

// ---------------------------------------------------------------------------
// Wt[h][om], om = g*128+o: g=0 -> WF[o][h]; g=1..4 -> WG[o][g-1][h]
// ---------------------------------------------------------------------------
__global__ void k_wt(const float* __restrict__ WF, const float* __restrict__ WG,
                     float* __restrict__ Wt) {
    __shared__ float t[32][33];
    int g = blockIdx.z;
    int h0 = blockIdx.x * 32, o0 = blockIdx.y * 32;
    int tx = threadIdx.x, ty = threadIdx.y;
    #pragma unroll
    for (int j = 0; j < 32; j += 8) {
        int o = o0 + ty + j;
        t[ty + j][tx] = (g == 0) ? WF[(size_t)o * HID + h0 + tx]
                                 : WG[((size_t)o * NF + (g - 1)) * HID + h0 + tx];
    }
    __syncthreads();
    #pragma unroll
    for (int j = 0; j < 32; j += 8)
        Wt[(size_t)(h0 + ty + j) * OM + g * HID + o0 + tx] = t[tx][ty + j];
}

// ---------------------------------------------------------------------------
// At2[m][h][o] = {A[0][m][o][h], A[1][m][o][h]}
// ---------------------------------------------------------------------------
__global__ void k_at2(const float* __restrict__ A, float2* __restrict__ At2) {
    __shared__ float t0[32][33], t1[32][33];
    int m = blockIdx.z;
    int h0 = blockIdx.x * 32, o0 = blockIdx.y * 32;
    int tx = threadIdx.x, ty = threadIdx.y;
    const float* A0 = A + (size_t)m * HID * HID;
    const float* A1 = A0 + (size_t)MODES * HID * HID;
    #pragma unroll
    for (int j = 0; j < 32; j += 8) {
        t0[ty + j][tx] = A0[(size_t)(o0 + ty + j) * HID + h0 + tx];
        t1[ty + j][tx] = A1[(size_t)(o0 + ty + j) * HID + h0 + tx];
    }
    __syncthreads();
    #pragma unroll
    for (int j = 0; j < 32; j += 8)
        At2[((size_t)m * HID + h0 + ty + j) * HID + o0 + tx] =
            make_float2(t0[tx][ty + j], t1[tx][ty + j]);
}

// ---------------------------------------------------------------------------
// Persistent solver: 256 WGs x 512 thr, 1 WG/CU (95 KB LDS).
// Phases/step: P1 IDFT (WG-local) -> P2 W-GEMM (WG-local) -> bar ->
//              P3a DFT(Hc)->hf -> bar -> P3b Av(LDS At2)+update | flush -> bar
// ---------------------------------------------------------------------------
__global__ __launch_bounds__(TPB, 1) void k_persist(
    const float* __restrict__ z0, const float* __restrict__ Ct,
    const float* __restrict__ St, const float2* __restrict__ T2x,
    const float* __restrict__ Wt, const float2* __restrict__ At2,
    const float* __restrict__ dxi, float* __restrict__ va,
    float* __restrict__ vb, float* __restrict__ Hc,
    float* __restrict__ hf, float* __restrict__ zbuf,
    float* __restrict__ out, int* __restrict__ barc)
{
    __shared__ float Cs[MODES][8];
    __shared__ float Ss[MODES][8];
    __shared__ float zsh[HID][9];
    __shared__ float dxs[8][NF];
    __shared__ float Ar[HID][64];      // persistent At2 slice (P3b WGs)
    __shared__ float Ai[HID][64];
    __shared__ float vsr[BATCH][HID];  // P3b v-slice; aliased as ftile by flush
    __shared__ float vsi[BATCH][HID];
    __shared__ float Hcl[NX][8];       // P3a Hc slice

    const int w = blockIdx.x;
    const int t = threadIdx.x;
    const int b = w >> 4;
    const int sub = w & 15;
    const int xg0 = sub * 8;
    const int m3 = w >> 1;             // P3b mode (w < 192)
    const int oh3 = w & 1;

    int nbar = 0;
    auto bar = [&]() {
        ++nbar;
        __syncthreads();
        if (t == 0) {
            __hip_atomic_fetch_add(barc, 1, __ATOMIC_RELEASE,
                                   __HIP_MEMORY_SCOPE_AGENT);
            while (__hip_atomic_load(barc, __ATOMIC_RELAXED,
                                     __HIP_MEMORY_SCOPE_AGENT) < NWG * nbar)
                __builtin_amdgcn_s_sleep(4);
            (void)__hip_atomic_load(barc, __ATOMIC_ACQUIRE,
                                    __HIP_MEMORY_SCOPE_AGENT);
        }
        __syncthreads();
    };

    // persistent P1 trig tables for this WG's x-tile
    for (int i = t; i < MODES * 8; i += TPB) {
        int m = i >> 3, xl = i & 7;
        Cs[m][xl] = Ct[m * NX + xg0 + xl];
        Ss[m][xl] = St[m * NX + xg0 + xl];
    }
    // persistent At2 slice -> LDS (P3b WGs only): 128 h x 64 o
    if (w < 192) {
        const float2* asrc = At2 + ((size_t)m3 * HID) * HID + oh3 * 64;
        #pragma unroll
        for (int k = 0; k < 16; ++k) {
            int idx = t + k * TPB;
            int h = idx >> 6, ol = idx & 63;
            float2 a = asrc[(size_t)h * HID + ol];
            Ar[h][ol] = a.x;
            Ai[h][ol] = a.y;
        }
    }

    // ---- v0 phase: WG=(b, sub) computes v0[b][c][6 modes][h] ----
    {
        int h = t & 127, q = t >> 7;       // q 0..3
        int c = q & 1, mq = q >> 1;
        const float* zr = z0 + ((size_t)b * HID + h) * NX;
        const float* Tb = c ? St : Ct;
        #pragma unroll
        for (int j = 0; j < 3; ++j) {
            int m = sub * 6 + mq * 3 + j;
            const float* Trow = Tb + m * NX;
            float acc = 0.f;
            #pragma unroll 4
            for (int x = 0; x < NX; ++x) acc += zr[x] * Trow[x];
            if (c) acc = -acc;
            va[(((size_t)b * 2 + c) * MODES + m) * HID + h] = acc;
        }
    }
    bar();

    float* vcur = va;
    float* vnxt = vb;

    for (int step = 0; step < NT; ++step) {
        const int last = (step == NT - 1);

        // ---- P1: IDFT -> zsh (LDS) + zbuf slice ----
        {
            if (!last && t < 32)
                dxs[t >> 2][t & 3] =
                    dxi[(((size_t)step * BATCH + b) * NX + xg0 + (t >> 2)) * NF + (t & 3)];
            int h = t & 127, xp = t >> 7;
            int x0 = xp * 2;
            const float* vr = vcur + ((size_t)b * 2) * MODES * HID + h;
            const float* vi = vr + (size_t)MODES * HID;
            float a0 = 0.f, a1 = 0.f;
            #pragma unroll 4
            for (int m = 0; m < MODES; ++m) {
                float r = vr[m * HID], im = vi[m * HID];
                a0 += r * Cs[m][x0]     - im * Ss[m][x0];
                a1 += r * Cs[m][x0 + 1] - im * Ss[m][x0 + 1];
            }
            a0 *= 0.0078125f; a1 *= 0.0078125f;
            zsh[h][x0] = a0; zsh[h][x0 + 1] = a1;
            float* zsl = zbuf + (size_t)(step & 15) * ZSZ + ((size_t)b * NX + xg0) * HID;
            zsl[(size_t)x0 * HID + h] = a0;
            zsl[(size_t)(x0 + 1) * HID + h] = a1;
        }
        __syncthreads();
        if (last) { bar(); break; }

        // ---- P2 (WG-local): W-GEMM + tanh + dxi combine -> Hc ----
        {
            int x = t >> 6, oml = t & 63;
            float acc[10] = {0,0,0,0,0,0,0,0,0,0};
            const float* wp = Wt + oml;
            #pragma unroll 2
            for (int h = 0; h < HID; ++h) {
                float zv = zsh[h][x];                 // wave-broadcast
                const float* wr = wp + (size_t)h * OM;
                #pragma unroll
                for (int j = 0; j < 10; ++j)
                    acc[j] += wr[j * 64] * zv;
            }
            float d0 = dxs[x][0], d1 = dxs[x][1], d2 = dxs[x][2], d3 = dxs[x][3];
            #pragma unroll
            for (int oh = 0; oh < 2; ++oh) {
                float hv = tanhf(acc[oh])
                         + tanhf(acc[2 + oh]) * d0
                         + tanhf(acc[4 + oh]) * d1
                         + tanhf(acc[6 + oh]) * d2
                         + tanhf(acc[8 + oh]) * d3;
                Hc[((size_t)b * NX + xg0 + x) * HID + oh * 64 + oml] = hv;
            }
        }
        bar();

        // ---- P3a: DFT of Hc -> hf.  WG=(b, o-tile=sub) ----
        {
            #pragma unroll
            for (int k = 0; k < 2; ++k) {
                int idx = t + k * TPB;
                int ol = idx & 7, xx = idx >> 3;
                Hcl[xx][ol] = Hc[((size_t)b * NX + xx) * HID + sub * 8 + ol];
            }
            __syncthreads();
            int ol = t >> 6, m1 = t & 63;
            bool two = (m1 < 32);
            int m2 = m1 + 64;
            float fre1 = 0, fim1 = 0, fre2 = 0, fim2 = 0;
            #pragma unroll 2
            for (int x = 0; x < NX; ++x) {
                float hv = Hcl[x][ol];                // wave-broadcast
                float2 ta = T2x[x * MODES + m1];      // coalesced 512B
                fre1 += hv * ta.x; fim1 -= hv * ta.y;
                if (two) {
                    float2 tb2 = T2x[x * MODES + m2];
                    fre2 += hv * tb2.x; fim2 -= hv * tb2.y;
                }
            }
            size_t hb0 = ((size_t)(b * 2 + 0) * 16 + sub) * HFST;
            size_t hb1 = ((size_t)(b * 2 + 1) * 16 + sub) * HFST;
            hf[hb0 + m1 * 8 + ol] = fre1;
            hf[hb1 + m1 * 8 + ol] = fim1;
            if (two) {
                hf[hb0 + m2 * 8 + ol] = fre2;
                hf[hb1 + m2 * 8 + ol] = fim2;
            }
            __syncthreads();
        }
        bar();

        // ---- P3b: Av (LDS At2) + update (w<192); flush (w>=192) ----
        if (w < 192) {
            #pragma unroll
            for (int k = 0; k < 8; ++k) {
                int idx = t + k * TPB;
                int h = idx & 127, bc = idx >> 7;
                int bb = bc >> 1, c = bc & 1;
                float vv = vcur[(((size_t)bb * 2 + c) * MODES + m3) * HID + h];
                if (c) vsi[bb][h] = vv; else vsr[bb][h] = vv;
            }
            __syncthreads();
            int ol = t & 63, bq = t >> 6;       // 8 bq x 64 ol
            int o = oh3 * 64 + ol;
            int b0 = bq * 2;
            float are0 = 0, aim0 = 0, are1 = 0, aim1 = 0;
            #pragma unroll 4
            for (int h = 0; h < HID; ++h) {
                float ax = Ar[h][ol], ay = Ai[h][ol];   // 2-way alias: free
                float r0 = vsr[b0][h],     i0 = vsi[b0][h];
                float r1 = vsr[b0 + 1][h], i1 = vsi[b0 + 1][h];
                are0 += ax * r0 - ay * i0;
                aim0 += ay * r0 - ax * i0;
                are1 += ax * r1 - ay * i1;
                aim1 += ay * r1 - ax * i1;
            }
            int sub_r = o >> 3, ol8 = o & 7;
            #pragma unroll
            for (int jb = 0; jb < 2; ++jb) {
                int bb = b0 + jb;
                float are = jb ? are1 : are0;
                float aim = jb ? aim1 : aim0;
                float fre = hf[((size_t)(bb * 2 + 0) * 16 + sub_r) * HFST + m3 * 8 + ol8];
                float fim = hf[((size_t)(bb * 2 + 1) * 16 + sub_r) * HFST + m3 * 8 + ol8];
                vnxt[(((size_t)bb * 2 + 0) * MODES + m3) * HID + o] = vsr[bb][o] + are + fre;
                vnxt[(((size_t)bb * 2 + 1) * MODES + m3) * HID + o] = vsi[bb][o] + aim + fim;
            }
            __syncthreads();
        } else if ((step & 15) == 15) {
            int w2 = w - 192;
            int fb = w2 >> 2, x0 = (w2 & 3) * 32;
            float* ftile = &vsr[0][0];     // 16*128 floats
            int t0 = step - 15;
            for (int xi2 = 0; xi2 < 32; ++xi2) {
                int x = x0 + xi2;
                #pragma unroll
                for (int k = 0; k < 4; ++k) {
                    int tt = (t >> 7) + k * 4;
                    ftile[tt * HID + (t & 127)] =
                        zbuf[(((size_t)tt * BATCH + fb) * NX + x) * HID + (t & 127)];
                }
                __syncthreads();
                int h = t >> 2, tq = t & 3;
                float4 v4;
                v4.x = ftile[(tq * 4 + 0) * HID + h];
                v4.y = ftile[(tq * 4 + 1) * HID + h];
                v4.z = ftile[(tq * 4 + 2) * HID + h];
                v4.w = ftile[(tq * 4 + 3) * HID + h];
                *(float4*)&out[(((size_t)fb * HID + h) * NX + x) * NT + t0 + tq * 4] = v4;
                __syncthreads();
            }
        }
        bar();

        float* tmp = vcur; vcur = vnxt; vnxt = tmp;
    }

    // ---- final flush: all 256 WGs, columns 48..63 ----
    {
        float* ftile = &vsr[0][0];
        int x0 = sub * 8;
        for (int xi2 = 0; xi2 < 8; ++xi2) {
            int x = x0 + xi2;
            #pragma unroll
            for (int k = 0; k < 4; ++k) {
                int tt = (t >> 7) + k * 4;
                ftile[tt * HID + (t & 127)] =
                    zbuf[(((size_t)tt * BATCH + b) * NX + x) * HID + (t & 127)];
            }
            __syncthreads();
            int h = t >> 2, tq = t & 3;
            float4 v4;
            v4.x = ftile[(tq * 4 + 0) * HID + h];
            v4.y = ftile[(tq * 4 + 1) * HID + h];
            v4.z = ftile[(tq * 4 + 2) * HID + h];
            v4.w = ftile[(tq * 4 + 3) * HID + h];
            *(float4*)&out[(((size_t)b * HID + h) * NX + x) * NT + 48 + tq * 4] = v4;
            __syncthreads();
        }
    }
}

// ---------------------------------------------------------------------------
extern "C" void kernel_launch(void* const* d_in, const int* in_sizes, int n_in,
                              void* d_out, int out_size, void* d_ws, size_t ws_size,
                              hipStream_t stream) {
    const float* z0 = (const float*)d_in[0];
    const float* xi = (const float*)d_in[1];
    const float* A  = (const float*)d_in[2];
    const float* WF = (const float*)d_in[3];
    const float* WG = (const float*)d_in[4];
    float* out = (float*)d_out;

    float* ws = (float*)d_ws;
    size_t off = 0;
    auto alloc = [&](size_t n) { float* p = ws + off; off += n; return p; };

    float*  Ct   = alloc((size_t)MODES * NX);
    float*  St   = alloc((size_t)MODES * NX);
    float2* T2x  = (float2*)alloc((size_t)NX * MODES * 2);
    float*  Wt   = alloc((size_t)HID * OM);
    float2* At2  = (float2*)alloc((size_t)MODES * HID * HID * 2);
    float*  va   = alloc((size_t)BATCH * 2 * MODES * HID);
    float*  vb   = alloc((size_t)BATCH * 2 * MODES * HID);
    float*  Hcb  = alloc((size_t)BATCH * NX * HID);
    float*  hfb  = alloc((size_t)BATCH * 2 * 16 * HFST);
    float*  dxib = alloc((size_t)(NT - 1) * BATCH * NX * NF);
    float*  zbuf = alloc(16 * ZSZ);
    int*    barc = (int*)alloc(64);

    hipMemsetAsync(barc, 0, 64 * sizeof(int), stream);
    k_tables<<<MODES, 128, 0, stream>>>(Ct, St, T2x);
    {
        int total = (NT - 1) * BATCH * NX * NF;
        k_dxi<<<(total + 255) / 256, 256, 0, stream>>>(xi, dxib);
    }
    k_wt<<<dim3(4, 4, 5), dim3(32, 8), 0, stream>>>(WF, WG, Wt);
    k_at2<<<dim3(4, 4, MODES), dim3(32, 8), 0, stream>>>(A, At2);

    k_persist<<<NWG, TPB, 0, stream>>>(z0, Ct, St, T2x, Wt, At2, dxib,
                                       va, vb, Hcb, hfb, zbuf, out, barc);
}

// Round 8
// 5517.423 us; speedup vs baseline: 1.2756x; 1.2756x over previous
//
#include <hip/hip_runtime.h>
#include <math.h>

#define BATCH 16
#define HID   128
#define NX    128
#define NF    4
#define NT    64
#define MODES 96
#define OM    (5 * HID)     // 640 fused W rows (F + 4*G)
#define ZSZ   ((size_t)BATCH * HID * NX)

// ---------------------------------------------------------------------------
// Tables: k_m=(80+m)%128. Ct/St scalar m-major; T2m[m][x]={c,s}; T2x[x][m].
// ---------------------------------------------------------------------------
__global__ void k_tables(float* __restrict__ C, float* __restrict__ S,
                         float2* __restrict__ T2m, float2* __restrict__ T2x) {
    int m = blockIdx.x, x = threadIdx.x;
    if (x < NX) {
        int k = (80 + m) % NX;
        float ang = (float)((k * x) & (NX - 1)) * (2.0f * (float)M_PI / (float)NX);
        float c = cosf(ang), s = sinf(ang);
        C[m * NX + x] = c;
        S[m * NX + x] = s;
        T2m[m * NX + x] = make_float2(c, s);
        T2x[x * MODES + m] = make_float2(c, s);
    }
}

// ---------------------------------------------------------------------------
// dxi[t][b][x][n] = xi[b,n,x,t+1] - xi[b,n,x,t]
// ---------------------------------------------------------------------------
__global__ void k_dxi(const float* __restrict__ xi, float* __restrict__ dxi) {
    int idx = blockIdx.x * blockDim.x + threadIdx.x;
    const int total = (NT - 1) * BATCH * NX * NF;
    if (idx < total) {
        int n = idx & (NF - 1);
        int x = (idx >> 2) & (NX - 1);
        int b = (idx >> 9) & (BATCH - 1);
        int t = idx >> 13;
        const float* base = xi + (((size_t)b * NF + n) * NX + x) * NT;
        dxi[idx] = base[t + 1] - base[t];
    }
}

// ---------------------------------------------------------------------------
// Wt[h][om], om = g*128+o: g=0 -> WF[o][h]; g=1..4 -> WG[o][g-1][h]
// ---------------------------------------------------------------------------
__global__ void k_wt(const float* __restrict__ WF, const float* __restrict__ WG,
                     float* __restrict__ Wt) {
    __shared__ float t[32][33];
    int g = blockIdx.z;
    int h0 = blockIdx.x * 32, o0 = blockIdx.y * 32;
    int tx = threadIdx.x, ty = threadIdx.y;
    #pragma unroll
    for (int j = 0; j < 32; j += 8) {
        int o = o0 + ty + j;
        t[ty + j][tx] = (g == 0) ? WF[(size_t)o * HID + h0 + tx]
                                 : WG[((size_t)o * NF + (g - 1)) * HID + h0 + tx];
    }
    __syncthreads();
    #pragma unroll
    for (int j = 0; j < 32; j += 8)
        Wt[(size_t)(h0 + ty + j) * OM + g * HID + o0 + tx] = t[tx][ty + j];
}

// ---------------------------------------------------------------------------
// At2[m][h][o] = {A[0][m][o][h], A[1][m][o][h]}
// ---------------------------------------------------------------------------
__global__ void k_at2(const float* __restrict__ A, float2* __restrict__ At2) {
    __shared__ float t0[32][33], t1[32][33];
    int m = blockIdx.z;
    int h0 = blockIdx.x * 32, o0 = blockIdx.y * 32;
    int tx = threadIdx.x, ty = threadIdx.y;
    const float* A0 = A + (size_t)m * HID * HID;
    const float* A1 = A0 + (size_t)MODES * HID * HID;
    #pragma unroll
    for (int j = 0; j < 32; j += 8) {
        t0[ty + j][tx] = A0[(size_t)(o0 + ty + j) * HID + h0 + tx];
        t1[ty + j][tx] = A1[(size_t)(o0 + ty + j) * HID + h0 + tx];
    }
    __syncthreads();
    #pragma unroll
    for (int j = 0; j < 32; j += 8)
        At2[((size_t)m * HID + h0 + ty + j) * HID + o0 + tx] =
            make_float2(t0[tx][ty + j], t1[tx][ty + j]);
}

// ---------------------------------------------------------------------------
// v0[b][c][m][h]: band-limited shifted FFT of z0 (one-time). grid (96,16).
// ---------------------------------------------------------------------------
__global__ __launch_bounds__(256) void k_v0(const float* __restrict__ z0,
                                            const float* __restrict__ C,
                                            const float* __restrict__ S,
                                            float* __restrict__ v) {
    int m = blockIdx.x, b = blockIdx.y;
    int h = threadIdx.x & 127;
    int c = threadIdx.x >> 7;
    const float* zr = z0 + ((size_t)b * HID + h) * NX;
    const float* T  = (c == 0) ? (C + m * NX) : (S + m * NX);
    float acc = 0.f;
    for (int x = 0; x < NX; ++x) acc += zr[x] * T[x];
    if (c) acc = -acc;
    v[(((size_t)b * 2 + c) * MODES + m) * HID + h] = acc;
}

// ---------------------------------------------------------------------------
// KA: IDFT z[b][h][x] = (1/128) sum_m (vre*C - vim*S).
// grid (2 xh, 16 ht, 16 b), 256 thr. v-slice (6KB) staged once per WG.
// ---------------------------------------------------------------------------
__global__ __launch_bounds__(256) void k_idft(
    const float* __restrict__ v, const float2* __restrict__ T2m,
    float* __restrict__ zslice)
{
    __shared__ float vsl[2][MODES][8];
    int xh = blockIdx.x, ht = blockIdx.y, b = blockIdx.z;
    int t = threadIdx.x;
    for (int i = t; i < 2 * MODES * 8; i += 256) {
        int j = i & 7, row = i >> 3;          // row = c*96+m
        int c = row >= MODES;
        int m = row - c * MODES;
        vsl[c][m][j] = v[(((size_t)b * 2 + c) * MODES + m) * HID + ht * 8 + j];
    }
    __syncthreads();
    int x = t & 63, hq = t >> 6;              // hq 0..3
    int xg = xh * 64 + x;
    int hl = hq * 2;
    float a0e = 0, a0o = 0, a1e = 0, a1o = 0;
    #pragma unroll 4
    for (int m = 0; m < MODES; m += 2) {
        float2 cs0 = T2m[(size_t)m * NX + xg];
        float2 cs1 = T2m[(size_t)(m + 1) * NX + xg];
        a0e += vsl[0][m][hl] * cs0.x     - vsl[1][m][hl] * cs0.y;
        a1e += vsl[0][m][hl + 1] * cs0.x - vsl[1][m][hl + 1] * cs0.y;
        a0o += vsl[0][m + 1][hl] * cs1.x     - vsl[1][m + 1][hl] * cs1.y;
        a1o += vsl[0][m + 1][hl + 1] * cs1.x - vsl[1][m + 1][hl + 1] * cs1.y;
    }
    float a0 = (a0e + a0o) * 0.0078125f;
    float a1 = (a1e + a1o) * 0.0078125f;
    int h = ht * 8 + hl;
    zslice[((size_t)b * HID + h) * NX + xg]       = a0;
    zslice[((size_t)b * HID + h + 1) * NX + xg]   = a1;
}

// ---------------------------------------------------------------------------
// KB: Hc[b][x][o] = tanh(F) + sum_n tanh(G_n)*dxi_n.
// grid (4 og, 16 xt, 16 b), 256 thr (32 o x 8 x). 5 indep acc chains.
// ---------------------------------------------------------------------------
__global__ __launch_bounds__(256) void k_wgemm(
    const float* __restrict__ zslice, const float* __restrict__ Wt,
    const float* __restrict__ dxi, float* __restrict__ Hc, int step)
{
    __shared__ float zsh[HID][8];
    __shared__ float dxs[8][NF];
    int og = blockIdx.x, xt = blockIdx.y, b = blockIdx.z;
    int t = threadIdx.x;
    for (int i = t; i < HID * 8; i += 256) {
        int xl = i & 7, h = i >> 3;
        zsh[h][xl] = zslice[((size_t)b * HID + h) * NX + xt * 8 + xl];
    }
    if (t < 32)
        dxs[t >> 2][t & 3] =
            dxi[(((size_t)step * BATCH + b) * NX + xt * 8 + (t >> 2)) * NF + (t & 3)];
    __syncthreads();
    int ol = t & 31, x = t >> 5;
    int o = og * 32 + ol;
    float acc[5] = {0, 0, 0, 0, 0};
    const float* wp = Wt + o;
    #pragma unroll 2
    for (int h = 0; h < HID; ++h) {
        float zv = zsh[h][x];                 // 2 bcast addrs/wave: free
        const float* wr = wp + (size_t)h * OM;
        #pragma unroll
        for (int g = 0; g < 5; ++g) acc[g] += wr[g * 128] * zv;
    }
    float hv = tanhf(acc[0])
             + tanhf(acc[1]) * dxs[x][0]
             + tanhf(acc[2]) * dxs[x][1]
             + tanhf(acc[3]) * dxs[x][2]
             + tanhf(acc[4]) * dxs[x][3];
    Hc[((size_t)b * NX + xt * 8 + x) * HID + o] = hv;
}

// ---------------------------------------------------------------------------
// KC: hf[c][m][b][o] = DFT_x(Hc). grid (16 ot, 16 b), 256 thr (8 o x 32 mq),
// each thread 3 modes. Tables read coalesced from L2 (no LDS restage).
// ---------------------------------------------------------------------------
__global__ __launch_bounds__(256) void k_dft(
    const float* __restrict__ Hc, const float2* __restrict__ T2x,
    float* __restrict__ hf)
{
    __shared__ float Hcl[NX][8];
    int ot = blockIdx.x, b = blockIdx.y;
    int t = threadIdx.x;
    for (int i = t; i < NX * 8; i += 256) {
        int ol = i & 7, x = i >> 3;
        Hcl[x][ol] = Hc[((size_t)b * NX + x) * HID + ot * 8 + ol];
    }
    __syncthreads();
    int ol = t & 7, mq = t >> 3;              // mq 0..31
    float re0 = 0, im0 = 0, re1 = 0, im1 = 0, re2 = 0, im2 = 0;
    #pragma unroll 2
    for (int x = 0; x < NX; ++x) {
        float hv = Hcl[x][ol];
        float2 t0 = T2x[(size_t)x * MODES + mq];
        float2 t1 = T2x[(size_t)x * MODES + mq + 32];
        float2 t2 = T2x[(size_t)x * MODES + mq + 64];
        re0 += hv * t0.x; im0 -= hv * t0.y;
        re1 += hv * t1.x; im1 -= hv * t1.y;
        re2 += hv * t2.x; im2 -= hv * t2.y;
    }
    int o = ot * 8 + ol;
    size_t bo = (size_t)b * HID + o;
    size_t cstr = (size_t)MODES * BATCH * HID;
    hf[(size_t)(mq)      * BATCH * HID + bo]        = re0;
    hf[(size_t)(mq + 32) * BATCH * HID + bo]        = re1;
    hf[(size_t)(mq + 64) * BATCH * HID + bo]        = re2;
    hf[cstr + (size_t)(mq)      * BATCH * HID + bo] = im0;
    hf[cstr + (size_t)(mq + 32) * BATCH * HID + bo] = im1;
    hf[cstr + (size_t)(mq + 64) * BATCH * HID + bo] = im2;
}

// ---------------------------------------------------------------------------
// KD: vout = vin + Av + hf. grid (4 oq, 2 bp, 96 m), 256 thr.
//   re = A0 r - A1 i; im = A1 r - A0 i  (faithful signs)
// ---------------------------------------------------------------------------
__global__ __launch_bounds__(256) void k_update(
    const float* __restrict__ vin, const float2* __restrict__ At2,
    const float* __restrict__ hf, float* __restrict__ vout)
{
    __shared__ float2 vs2[8][HID];
    int oq = blockIdx.x, bp = blockIdx.y, m = blockIdx.z;
    int tid = threadIdx.x;
    for (int f = tid; f < 8 * HID; f += 256) {
        int bl = f >> 7, h = f & 127;
        int b = bp * 8 + bl;
        size_t base = (((size_t)b * 2) * MODES + m) * HID + h;
        vs2[bl][h] = make_float2(vin[base], vin[base + (size_t)MODES * HID]);
    }
    __syncthreads();
    int o = oq * 32 + (tid & 31), bq = tid >> 5;  // bq 0..7 -> 1 batch pair? no: 8 bq x 1
    // thread handles 4 batches: bl = bq*... use 2 passes of 4? Simplest: 4 batches.
    float fre[4], fim[4], are[4], aim[4];
    #pragma unroll
    for (int j = 0; j < 4; ++j) { fre[j] = fim[j] = are[j] = aim[j] = 0.f; }
    int bl0 = (bq & 1) * 4;                       // bq even/odd -> batch half of this bp
    int sub = bq >> 1;                            // 0..3: o replication? no — split h
    (void)sub;
    // Simpler and proven (round-3 structure): each thread does 4 batches, full h.
    const float2* a2 = At2 + ((size_t)m * HID) * HID + o;
    #pragma unroll 2
    for (int h = 0; h < HID; ++h) {
        float2 a = a2[(size_t)h * HID];
        #pragma unroll
        for (int j = 0; j < 4; ++j) {
            float2 vv = vs2[bl0 + j][h];
            are[j] += a.x * vv.x - a.y * vv.y;
            aim[j] += a.y * vv.x - a.x * vv.y;
        }
    }
    if (bq & 2) return;                           // lanes with bq>=2 duplicated work; drop
    #pragma unroll
    for (int j = 0; j < 4; ++j) {
        int bl = bl0 + j, b = bp * 8 + bl;
        size_t mb = ((size_t)m * BATCH + b) * HID + o;
        float frev = hf[mb];
        float fimv = hf[(size_t)MODES * BATCH * HID + mb];
        float2 vo = vs2[bl][o];
        size_t ob = (((size_t)b * 2) * MODES + m) * HID + o;
        vout[ob] = vo.x + are[j] + frev;
        vout[ob + (size_t)MODES * HID] = vo.y + aim[j] + fimv;
    }
}

// ---------------------------------------------------------------------------
// Flush: zbuf[tt][b][h][x] (16 steps) -> out[b][h][x][t0+tt].
// grid (128 h, 16 b), 128 thr (lane = x). Full 64B lines per lane.
// ---------------------------------------------------------------------------
__global__ __launch_bounds__(128) void k_flush(const float* __restrict__ zbuf,
                                               float* __restrict__ out, int t0) {
    int h = blockIdx.x, b = blockIdx.y, x = threadIdx.x;
    float vals[16];
    #pragma unroll
    for (int tt = 0; tt < 16; ++tt)
        vals[tt] = zbuf[(size_t)tt * ZSZ + ((size_t)b * HID + h) * NX + x];
    float* dst = out + (((size_t)b * HID + h) * NX + x) * NT + t0;
    #pragma unroll
    for (int q = 0; q < 4; ++q)
        ((float4*)dst)[q] = make_float4(vals[q * 4], vals[q * 4 + 1],
                                        vals[q * 4 + 2], vals[q * 4 + 3]);
}

// ---------------------------------------------------------------------------
extern "C" void kernel_launch(void* const* d_in, const int* in_sizes, int n_in,
                              void* d_out, int out_size, void* d_ws, size_t ws_size,
                              hipStream_t stream) {
    const float* z0 = (const float*)d_in[0];
    const float* xi = (const float*)d_in[1];
    const float* A  = (const float*)d_in[2];
    const float* WF = (const float*)d_in[3];
    const float* WG = (const float*)d_in[4];
    float* out = (float*)d_out;

    float* ws = (float*)d_ws;
    size_t off = 0;
    auto alloc = [&](size_t n) { float* p = ws + off; off += n; return p; };

    float*  Ct   = alloc((size_t)MODES * NX);
    float*  St   = alloc((size_t)MODES * NX);
    float2* T2m  = (float2*)alloc((size_t)MODES * NX * 2);
    float2* T2x  = (float2*)alloc((size_t)NX * MODES * 2);
    float*  Wt   = alloc((size_t)HID * OM);
    float2* At2  = (float2*)alloc((size_t)MODES * HID * HID * 2);
    float*  va   = alloc((size_t)BATCH * 2 * MODES * HID);
    float*  vb   = alloc((size_t)BATCH * 2 * MODES * HID);
    float*  Hcb  = alloc((size_t)BATCH * NX * HID);
    float*  hfb  = alloc((size_t)2 * MODES * BATCH * HID);
    float*  dxib = alloc((size_t)(NT - 1) * BATCH * NX * NF);
    float*  zbuf = alloc(16 * ZSZ);

    // setup
    k_tables<<<MODES, 128, 0, stream>>>(Ct, St, T2m, T2x);
    {
        int total = (NT - 1) * BATCH * NX * NF;
        k_dxi<<<(total + 255) / 256, 256, 0, stream>>>(xi, dxib);
    }
    k_wt<<<dim3(4, 4, 5), dim3(32, 8), 0, stream>>>(WF, WG, Wt);
    k_at2<<<dim3(4, 4, MODES), dim3(32, 8), 0, stream>>>(A, At2);
    k_v0<<<dim3(MODES, BATCH), 256, 0, stream>>>(z0, Ct, St, va);

    float* vcur = va;
    float* vnxt = vb;
    for (int i = 0; i < NT - 1; ++i) {
        float* zslice = zbuf + (size_t)(i & 15) * ZSZ;
        k_idft<<<dim3(2, 16, BATCH), 256, 0, stream>>>(vcur, T2m, zslice);
        k_wgemm<<<dim3(4, 16, BATCH), 256, 0, stream>>>(zslice, Wt, dxib, Hcb, i);
        k_dft<<<dim3(16, BATCH), 256, 0, stream>>>(Hcb, T2x, hfb);
        k_update<<<dim3(4, 2, MODES), 256, 0, stream>>>(vcur, At2, hfb, vnxt);
        float* t = vcur; vcur = vnxt; vnxt = t;
        if ((i & 15) == 15)
            k_flush<<<dim3(HID, BATCH), 128, 0, stream>>>(zbuf, out, i - 15);
    }
    {
        float* zslice = zbuf + (size_t)((NT - 1) & 15) * ZSZ;
        k_idft<<<dim3(2, 16, BATCH), 256, 0, stream>>>(vcur, T2m, zslice);
        k_flush<<<dim3(HID, BATCH), 128, 0, stream>>>(zbuf, out, NT - 16);
    }
}

// Round 9
// 4159.004 us; speedup vs baseline: 1.6922x; 1.3266x over previous
//
#include <hip/hip_runtime.h>
#include <math.h>

#define BATCH 16
#define HID   128
#define NX    128
#define NF    4
#define NT    64
#define MODES 96
#define OM    (5 * HID)     // 640 fused W rows (F + 4*G)
#define NWG   256
#define TPB   1024
#define GSZ   16            // WGs per group (one group per batch)
#define ZSZ   ((size_t)BATCH * NX * HID)   // zbuf slice: [b][x][h]

// ---------------------------------------------------------------------------
// Tables: k_m=(80+m)%128. Ct/St scalar m-major; T2m[m][x]={c,s}.
// ---------------------------------------------------------------------------
__global__ void k_tables(float* __restrict__ C, float* __restrict__ S,
                         float2* __restrict__ T2m) {
    int m = blockIdx.x, x = threadIdx.x;
    if (x < NX) {
        int k = (80 + m) % NX;
        float ang = (float)((k * x) & (NX - 1)) * (2.0f * (float)M_PI / (float)NX);
        float c = cosf(ang), s = sinf(ang);
        C[m * NX + x] = c;
        S[m * NX + x] = s;
        T2m[m * NX + x] = make_float2(c, s);
    }
}

// ---------------------------------------------------------------------------
// dxi[t][b][x][n] = xi[b,n,x,t+1] - xi[b,n,x,t]
// ---------------------------------------------------------------------------
__global__ void k_dxi(const float* __restrict__ xi, float* __restrict__ dxi) {
    int idx = blockIdx.x * blockDim.x + threadIdx.x;
    const int total = (NT - 1) * BATCH * NX * NF;
    if (idx < total) {
        int n = idx & (NF - 1);
        int x = (idx >> 2) & (NX - 1);
        int b = (idx >> 9) & (BATCH - 1);
        int t = idx >> 13;
        const float* base = xi + (((size_t)b * NF + n) * NX + x) * NT;
        dxi[idx] = base[t + 1] - base[t];
    }
}

// ---------------------------------------------------------------------------
// Wt[h][om], om = g*128+o: g=0 -> WF[o][h]; g=1..4 -> WG[o][g-1][h]
// ---------------------------------------------------------------------------
__global__ void k_wt(const float* __restrict__ WF, const float* __restrict__ WG,
                     float* __restrict__ Wt) {
    __shared__ float t[32][33];
    int g = blockIdx.z;
    int h0 = blockIdx.x * 32, o0 = blockIdx.y * 32;
    int tx = threadIdx.x, ty = threadIdx.y;
    #pragma unroll
    for (int j = 0; j < 32; j += 8) {
        int o = o0 + ty + j;
        t[ty + j][tx] = (g == 0) ? WF[(size_t)o * HID + h0 + tx]
                                 : WG[((size_t)o * NF + (g - 1)) * HID + h0 + tx];
    }
    __syncthreads();
    #pragma unroll
    for (int j = 0; j < 32; j += 8)
        Wt[(size_t)(h0 + ty + j) * OM + g * HID + o0 + tx] = t[tx][ty + j];
}

// ---------------------------------------------------------------------------
// At2[m][h][o] = {A[0][m][o][h], A[1][m][o][h]}
// ---------------------------------------------------------------------------
__global__ void k_at2(const float* __restrict__ A, float2* __restrict__ At2) {
    __shared__ float t0[32][33], t1[32][33];
    int m = blockIdx.z;
    int h0 = blockIdx.x * 32, o0 = blockIdx.y * 32;
    int tx = threadIdx.x, ty = threadIdx.y;
    const float* A0 = A + (size_t)m * HID * HID;
    const float* A1 = A0 + (size_t)MODES * HID * HID;
    #pragma unroll
    for (int j = 0; j < 32; j += 8) {
        t0[ty + j][tx] = A0[(size_t)(o0 + ty + j) * HID + h0 + tx];
        t1[ty + j][tx] = A1[(size_t)(o0 + ty + j) * HID + h0 + tx];
    }
    __syncthreads();
    #pragma unroll
    for (int j = 0; j < 32; j += 8)
        At2[((size_t)m * HID + h0 + ty + j) * HID + o0 + tx] =
            make_float2(t0[tx][ty + j], t1[tx][ty + j]);
}

// ---------------------------------------------------------------------------
// Persistent group-local solver: 16 groups x 16 WGs x 1024 thr.
// Group g owns batch b=g. Barriers are 16-arrival, per-group cacheline.
// Step: P1 IDFT (x-part) -> gbar -> P2 [WGEMM+combine+DFT+Av+update] (o-part)
//       -> gbar.  Flush of out is WG-local (each WG owns its x-tile of zbuf).
// ---------------------------------------------------------------------------
__global__ __launch_bounds__(TPB, 1) void k_solve(
    const float* __restrict__ z0, const float* __restrict__ Ct,
    const float* __restrict__ St, const float2* __restrict__ T2m,
    const float* __restrict__ Wt, const float2* __restrict__ At2,
    const float* __restrict__ dxi, float* __restrict__ va,
    float* __restrict__ vb, float* __restrict__ zbuf,
    float* __restrict__ out, int* __restrict__ barc)
{
    __shared__ float Csh[MODES][8];       // P1 trig (persistent)
    __shared__ float Ssh[MODES][8];
    __shared__ float zsl[HID][129];       // P2a z (staged, padded)
    __shared__ float Wsl[HID][41];        // P2a W slice (40 cols, padded)
    __shared__ float Hcl[NX][9];          // P2a->P2b combined H (padded)
    __shared__ float dxs[NX][NF];         // P2a dxi slice

    const int w = blockIdx.x;
    const int t = threadIdx.x;
    const int grp = w >> 4;               // batch
    const int j = w & 15;                 // WG role within group
    const int b = grp;
    const int xg0 = j * 8;                // P1/flush x-tile
    const int o0 = j * 8;                 // P2 o-tile

    int nbar = 0;
    int* ctr = barc + grp * 64;           // 256B-separated per-group counter
    auto gbar = [&]() {
        ++nbar;
        __syncthreads();
        if (t == 0) {
            __hip_atomic_fetch_add(ctr, 1, __ATOMIC_RELEASE,
                                   __HIP_MEMORY_SCOPE_AGENT);
            while (__hip_atomic_load(ctr, __ATOMIC_RELAXED,
                                     __HIP_MEMORY_SCOPE_AGENT) < GSZ * nbar)
                __builtin_amdgcn_s_sleep(2);
            (void)__hip_atomic_load(ctr, __ATOMIC_ACQUIRE,
                                    __HIP_MEMORY_SCOPE_AGENT);
        }
        __syncthreads();
    };

    // persistent P1 trig for this WG's x-tile
    if (t < MODES * 8) {
        int m = t >> 3, xp = t & 7;
        Csh[m][xp] = Ct[m * NX + xg0 + xp];
        Ssh[m][xp] = St[m * NX + xg0 + xp];
    }

    // ---- v0: WG j computes v0[b][c][m in 6-slice][h] ----
    {
        int h = t & 127, q = t >> 7;          // q 0..7
        int c = q & 1, mq = q >> 1;           // mq 0..3
        const float* zr = z0 + ((size_t)b * HID + h) * NX;
        #pragma unroll
        for (int jj = 0; jj < 2; ++jj) {
            int mm = mq + 4 * jj;
            if (mm < 6) {
                int m = j * 6 + mm;
                const float* Trow = (c ? St : Ct) + m * NX;
                float acc = 0.f;
                #pragma unroll 4
                for (int x = 0; x < NX; ++x) acc += zr[x] * Trow[x];
                if (c) acc = -acc;
                va[(((size_t)b * 2 + c) * MODES + m) * HID + h] = acc;
            }
        }
    }
    gbar();

    float* vcur = va;
    float* vnxt = vb;

    for (int step = 0; step < NT; ++step) {
        // ---- WG-local flush of completed 16-step window ----
        if (step > 0 && (step & 15) == 0) {
            int t0 = step - 16;
            int xl = t >> 7, h = t & 127;
            int x = xg0 + xl;
            float vals[16];
            #pragma unroll
            for (int tt = 0; tt < 16; ++tt)
                vals[tt] = zbuf[(size_t)tt * ZSZ + ((size_t)b * NX + x) * HID + h];
            float* dst = out + (((size_t)b * HID + h) * NX + x) * NT + t0;
            #pragma unroll
            for (int q = 0; q < 4; ++q)
                ((float4*)dst)[q] = make_float4(vals[q*4], vals[q*4+1],
                                                vals[q*4+2], vals[q*4+3]);
        }

        // ---- P1: IDFT -> zbuf[step&15][b][x][h] ----
        {
            int h = t & 127, xp = t >> 7;     // xp 0..7
            const float* vr = vcur + ((size_t)b * 2) * MODES * HID + h;
            const float* vi = vr + (size_t)MODES * HID;
            float acc = 0.f;
            #pragma unroll 4
            for (int m = 0; m < MODES; ++m) {
                acc += vr[m * HID] * Csh[m][xp] - vi[m * HID] * Ssh[m][xp];
            }
            acc *= 0.0078125f;
            zbuf[(size_t)(step & 15) * ZSZ + ((size_t)b * NX + xg0 + xp) * HID + h] = acc;
        }
        if (step == NT - 1) break;
        gbar();

        // ---- P2a: stage z + W-slice + dxi; W-GEMM + tanh/dxi -> Hcl ----
        {
            const float4* z4 = (const float4*)(zbuf + (size_t)(step & 15) * ZSZ
                                               + (size_t)b * NX * HID);
            #pragma unroll
            for (int k = 0; k < 4; ++k) {
                float4 v4 = z4[t + k * 1024];
                int idx = (t + k * 1024) * 4;
                int x = idx >> 7, h = idx & 127;
                zsl[h][x] = v4.x; zsl[h + 1][x] = v4.y;
                zsl[h + 2][x] = v4.z; zsl[h + 3][x] = v4.w;
            }
            #pragma unroll
            for (int k = 0; k < 5; ++k) {
                int idx = t + k * 1024;
                int h = idx / 40, col = idx - h * 40;   // col = g*8 + ol
                int g = col >> 3, ol = col & 7;
                Wsl[h][col] = Wt[(size_t)h * OM + g * HID + o0 + ol];
            }
            if (t < 512)
                dxs[t >> 2][t & 3] =
                    dxi[((size_t)step * BATCH + b) * NX * NF + t];
            __syncthreads();

            int ol = t & 7, x = t >> 3;       // 8 o x 128 x
            float acc[5] = {0, 0, 0, 0, 0};
            #pragma unroll 4
            for (int h = 0; h < HID; ++h) {
                float zv = zsl[h][x];
                #pragma unroll
                for (int g = 0; g < 5; ++g)
                    acc[g] += Wsl[h][g * 8 + ol] * zv;
            }
            float hv = tanhf(acc[0])
                     + tanhf(acc[1]) * dxs[x][0]
                     + tanhf(acc[2]) * dxs[x][1]
                     + tanhf(acc[3]) * dxs[x][2]
                     + tanhf(acc[4]) * dxs[x][3];
            Hcl[x][ol] = hv;
            __syncthreads();
        }

        // ---- P2b: DFT + Av + update, thread=(o_l, m), 768 active ----
        if (t < 768) {
            int ol = t & 7, m = t >> 3;
            int o = o0 + ol;
            // DFT over x
            float fre = 0.f, fim = 0.f;
            #pragma unroll 4
            for (int x = 0; x < NX; ++x) {
                float hv = Hcl[x][ol];
                float2 ts = T2m[(size_t)m * NX + x];
                fre += hv * ts.x;
                fim -= hv * ts.y;
            }
            // Av over h (faithful signs: re=A0r-A1i, im=A1r-A0i)
            const float2* a2 = At2 + ((size_t)m * HID) * HID + o;
            const float* vr = vcur + (((size_t)b * 2 + 0) * MODES + m) * HID;
            const float* vi = vcur + (((size_t)b * 2 + 1) * MODES + m) * HID;
            float are = 0.f, aim = 0.f;
            #pragma unroll 4
            for (int h = 0; h < HID; ++h) {
                float2 a = a2[(size_t)h * HID];
                float r = vr[h], i2 = vi[h];
                are += a.x * r - a.y * i2;
                aim += a.y * r - a.x * i2;
            }
            vnxt[(((size_t)b * 2 + 0) * MODES + m) * HID + o] = vr[o] + are + fre;
            vnxt[(((size_t)b * 2 + 1) * MODES + m) * HID + o] = vi[o] + aim + fim;
        }
        gbar();

        float* tmp = vcur; vcur = vnxt; vnxt = tmp;
    }

    // ---- final flush: columns 48..63 (all zbuf writes are WG-local) ----
    {
        int xl = t >> 7, h = t & 127;
        int x = xg0 + xl;
        float vals[16];
        #pragma unroll
        for (int tt = 0; tt < 16; ++tt)
            vals[tt] = zbuf[(size_t)tt * ZSZ + ((size_t)b * NX + x) * HID + h];
        float* dst = out + (((size_t)b * HID + h) * NX + x) * NT + 48;
        #pragma unroll
        for (int q = 0; q < 4; ++q)
            ((float4*)dst)[q] = make_float4(vals[q*4], vals[q*4+1],
                                            vals[q*4+2], vals[q*4+3]);
    }
}

// ---------------------------------------------------------------------------
extern "C" void kernel_launch(void* const* d_in, const int* in_sizes, int n_in,
                              void* d_out, int out_size, void* d_ws, size_t ws_size,
                              hipStream_t stream) {
    const float* z0 = (const float*)d_in[0];
    const float* xi = (const float*)d_in[1];
    const float* A  = (const float*)d_in[2];
    const float* WF = (const float*)d_in[3];
    const float* WG = (const float*)d_in[4];
    float* out = (float*)d_out;

    float* ws = (float*)d_ws;
    size_t off = 0;
    auto alloc = [&](size_t n) { float* p = ws + off; off += n; return p; };

    float*  Ct   = alloc((size_t)MODES * NX);
    float*  St   = alloc((size_t)MODES * NX);
    float2* T2m  = (float2*)alloc((size_t)MODES * NX * 2);
    float*  Wt   = alloc((size_t)HID * OM);
    float2* At2  = (float2*)alloc((size_t)MODES * HID * HID * 2);
    float*  va   = alloc((size_t)BATCH * 2 * MODES * HID);
    float*  vb   = alloc((size_t)BATCH * 2 * MODES * HID);
    float*  dxib = alloc((size_t)(NT - 1) * BATCH * NX * NF);
    float*  zbuf = alloc(16 * ZSZ);
    int*    barc = (int*)alloc(BATCH * 64);

    hipMemsetAsync(barc, 0, BATCH * 64 * sizeof(int), stream);
    k_tables<<<MODES, 128, 0, stream>>>(Ct, St, T2m);
    {
        int total = (NT - 1) * BATCH * NX * NF;
        k_dxi<<<(total + 255) / 256, 256, 0, stream>>>(xi, dxib);
    }
    k_wt<<<dim3(4, 4, 5), dim3(32, 8), 0, stream>>>(WF, WG, Wt);
    k_at2<<<dim3(4, 4, MODES), dim3(32, 8), 0, stream>>>(A, At2);

    k_solve<<<NWG, TPB, 0, stream>>>(z0, Ct, St, T2m, Wt, At2, dxib,
                                     va, vb, zbuf, out, barc);
}

// Round 10
// 3804.880 us; speedup vs baseline: 1.8497x; 1.0931x over previous
//
#include <hip/hip_runtime.h>
#include <math.h>

#define BATCH 16
#define HID   128
#define NX    128
#define NF    4
#define NT    64
#define MODES 96
#define NWG   256
#define TPB   1024
#define GSZ   16            // WGs per group (one group per batch)
#define ZSZ   ((size_t)BATCH * NX * HID)   // zbuf slice: [b][x][h]

// ---------------------------------------------------------------------------
// Tables: k_m=(80+m)%128. Ct/St scalar m-major; T2m[m][x]={c,s}.
// ---------------------------------------------------------------------------
__global__ void k_tables(float* __restrict__ C, float* __restrict__ S,
                         float2* __restrict__ T2m) {
    int m = blockIdx.x, x = threadIdx.x;
    if (x < NX) {
        int k = (80 + m) % NX;
        float ang = (float)((k * x) & (NX - 1)) * (2.0f * (float)M_PI / (float)NX);
        float c = cosf(ang), s = sinf(ang);
        C[m * NX + x] = c;
        S[m * NX + x] = s;
        T2m[m * NX + x] = make_float2(c, s);
    }
}

// ---------------------------------------------------------------------------
// dxi[t][b][x][n] = xi[b,n,x,t+1] - xi[b,n,x,t]
// ---------------------------------------------------------------------------
__global__ void k_dxi(const float* __restrict__ xi, float* __restrict__ dxi) {
    int idx = blockIdx.x * blockDim.x + threadIdx.x;
    const int total = (NT - 1) * BATCH * NX * NF;
    if (idx < total) {
        int n = idx & (NF - 1);
        int x = (idx >> 2) & (NX - 1);
        int b = (idx >> 9) & (BATCH - 1);
        int t = idx >> 13;
        const float* base = xi + (((size_t)b * NF + n) * NX + x) * NT;
        dxi[idx] = base[t + 1] - base[t];
    }
}

// ---------------------------------------------------------------------------
// Wt4[j][h][ol] = {WF[o][h], WG[o][0][h], WG[o][1][h], WG[o][2][h]},
// Wt1[j][h][ol] = WG[o][3][h], where o = j*8+ol.  16*128*8 entries.
// ---------------------------------------------------------------------------
__global__ void k_wt4(const float* __restrict__ WF, const float* __restrict__ WGm,
                      float4* __restrict__ Wt4, float* __restrict__ Wt1) {
    int idx = blockIdx.x * 256 + threadIdx.x;
    if (idx < 16 * HID * 8) {
        int ol = idx & 7, h = (idx >> 3) & 127, j = idx >> 10;
        int o = j * 8 + ol;
        Wt4[idx] = make_float4(WF[(size_t)o * HID + h],
                               WGm[((size_t)o * NF + 0) * HID + h],
                               WGm[((size_t)o * NF + 1) * HID + h],
                               WGm[((size_t)o * NF + 2) * HID + h]);
        Wt1[idx] = WGm[((size_t)o * NF + 3) * HID + h];
    }
}

// ---------------------------------------------------------------------------
// At2[m][h][o] = {A[0][m][o][h], A[1][m][o][h]}
// ---------------------------------------------------------------------------
__global__ void k_at2(const float* __restrict__ A, float2* __restrict__ At2) {
    __shared__ float t0[32][33], t1[32][33];
    int m = blockIdx.z;
    int h0 = blockIdx.x * 32, o0 = blockIdx.y * 32;
    int tx = threadIdx.x, ty = threadIdx.y;
    const float* A0 = A + (size_t)m * HID * HID;
    const float* A1 = A0 + (size_t)MODES * HID * HID;
    #pragma unroll
    for (int j = 0; j < 32; j += 8) {
        t0[ty + j][tx] = A0[(size_t)(o0 + ty + j) * HID + h0 + tx];
        t1[ty + j][tx] = A1[(size_t)(o0 + ty + j) * HID + h0 + tx];
    }
    __syncthreads();
    #pragma unroll
    for (int j = 0; j < 32; j += 8)
        At2[((size_t)m * HID + h0 + ty + j) * HID + o0 + tx] =
            make_float2(t0[tx][ty + j], t1[tx][ty + j]);
}

// ---------------------------------------------------------------------------
// Persistent group-local solver: 16 groups x 16 WGs x 1024 thr.
// v stored interleaved float2 [b][m][h]. Per step:
//   P1 IDFT (x-tile j)            -> gbar
//   P2a W-GEMM+tanh+dxi (o-tile j), Hc[b][x][o] global -> gbar
//   P2b DFT+Av+update (m-tile j: 6m x 128o, all coalesced) -> gbar
// ---------------------------------------------------------------------------
__global__ __launch_bounds__(TPB, 1) void k_solve(
    const float* __restrict__ z0, const float* __restrict__ Ct,
    const float* __restrict__ St, const float2* __restrict__ T2m,
    const float4* __restrict__ Wt4g, const float* __restrict__ Wt1g,
    const float2* __restrict__ At2, const float* __restrict__ dxi,
    float2* __restrict__ va, float2* __restrict__ vb,
    float* __restrict__ zbuf, float* __restrict__ Hc,
    float* __restrict__ out, int* __restrict__ barc)
{
    __shared__ float2 CS[MODES][8];     // P1 trig (persistent)        6 KB
    __shared__ float  zsl[NX][132];     // P2a z tile [x][h]          67.6 KB
    __shared__ float4 Wsl4[HID][8];     // P2a W (persistent)         16 KB
    __shared__ float  Wsl1[HID][9];     //                             4.6 KB
    __shared__ float  dxs[NX][5];       // P2a dxi (pad 5)             2.5 KB
    __shared__ float2 vsl[6][HID];      // P2b v slice                 6 KB

    const int w = blockIdx.x;
    const int t = threadIdx.x;
    const int b = w >> 4;               // group = batch
    const int j = w & 15;               // WG role
    const int xg0 = j * 8;              // P1/flush x-tile
    const int o0 = j * 8;               // P2a o-tile
    const int m0 = j * 6;               // P2b/v0 m-tile

    int nbar = 0;
    int* ctr = barc + b * 64;           // 256B-separated per-group counter
    auto gbar = [&]() {
        ++nbar;
        __syncthreads();
        if (t == 0) {
            __hip_atomic_fetch_add(ctr, 1, __ATOMIC_RELEASE,
                                   __HIP_MEMORY_SCOPE_AGENT);
            while (__hip_atomic_load(ctr, __ATOMIC_RELAXED,
                                     __HIP_MEMORY_SCOPE_AGENT) < GSZ * nbar)
                __builtin_amdgcn_s_sleep(2);
            (void)__hip_atomic_load(ctr, __ATOMIC_ACQUIRE,
                                    __HIP_MEMORY_SCOPE_AGENT);
        }
        __syncthreads();
    };

    // persistent P1 trig for x-tile
    if (t < MODES * 8) {
        int m = t >> 3, xp = t & 7;
        CS[m][xp] = T2m[m * NX + xg0 + xp];
    }
    // persistent W slice for o-tile (constant across steps)
    {
        int h = t >> 3, ol = t & 7;
        Wsl4[h][ol] = Wt4g[((size_t)j * HID + h) * 8 + ol];
        Wsl1[h][ol] = Wt1g[((size_t)j * HID + h) * 8 + ol];
    }

    // ---- v0: WG j computes v0[b][m-tile][h] (re,im) ----
    {
        int h = t & 127, q = t >> 7;        // q 0..7
        int c = q & 1, mq = q >> 1;         // mq 0..3
        const float* zr = z0 + ((size_t)b * HID + h) * NX;
        float* fva = (float*)va;
        #pragma unroll
        for (int jj = 0; jj < 2; ++jj) {
            int mm = mq + 4 * jj;
            if (mm < 6) {
                int m = m0 + mm;
                const float* Trow = (c ? St : Ct) + m * NX;
                float acc = 0.f;
                #pragma unroll 4
                for (int x = 0; x < NX; ++x) acc += zr[x] * Trow[x];
                if (c) acc = -acc;
                fva[(((size_t)b * MODES + m) * HID + h) * 2 + c] = acc;
            }
        }
    }
    gbar();

    float2* vcur = va;
    float2* vnxt = vb;

    for (int step = 0; step < NT; ++step) {
        // ---- WG-local flush of completed 16-step window ----
        if (step > 0 && (step & 15) == 0) {
            int t0 = step - 16;
            int xl = t >> 7, h = t & 127;
            int x = xg0 + xl;
            float vals[16];
            #pragma unroll
            for (int tt = 0; tt < 16; ++tt)
                vals[tt] = zbuf[(size_t)tt * ZSZ + ((size_t)b * NX + x) * HID + h];
            float* dst = out + (((size_t)b * HID + h) * NX + x) * NT + t0;
            #pragma unroll
            for (int q = 0; q < 4; ++q)
                ((float4*)dst)[q] = make_float4(vals[q*4], vals[q*4+1],
                                                vals[q*4+2], vals[q*4+3]);
        }

        // ---- P1: IDFT -> zbuf[step&15][b][x][h] ----
        {
            int h = t & 127, xp = t >> 7;   // xp 0..7
            const float2* vr = vcur + (size_t)b * MODES * HID + h;
            float acc = 0.f;
            #pragma unroll 4
            for (int m = 0; m < MODES; ++m) {
                float2 vv = vr[(size_t)m * HID];
                float2 cs = CS[m][xp];
                acc += vv.x * cs.x - vv.y * cs.y;
            }
            acc *= 0.0078125f;
            zbuf[(size_t)(step & 15) * ZSZ + ((size_t)b * NX + xg0 + xp) * HID + h] = acc;
        }
        if (step == NT - 1) break;
        gbar();

        // ---- P2a: W-GEMM + tanh + dxi -> Hc[b][x][o-tile] ----
        {
            const float4* z4 = (const float4*)(zbuf + (size_t)(step & 15) * ZSZ
                                               + (size_t)b * NX * HID);
            #pragma unroll
            for (int k = 0; k < 4; ++k) {
                int idx = t + k * 1024;
                int x = idx >> 5, h4 = (idx & 31) * 4;
                *(float4*)&zsl[x][h4] = z4[idx];
            }
            if (t < 512)
                dxs[t >> 2][t & 3] =
                    dxi[((size_t)step * BATCH + b) * NX * NF + t];
            __syncthreads();

            int ol = t & 7, x = t >> 3;     // 8 o x 128 x
            float a0 = 0.f, a1 = 0.f, a2 = 0.f, a3 = 0.f, a4 = 0.f;
            #pragma unroll 4
            for (int h = 0; h < HID; ++h) {
                float zv = zsl[x][h];
                float4 w4 = Wsl4[h][ol];
                float w1 = Wsl1[h][ol];
                a0 += w4.x * zv; a1 += w4.y * zv;
                a2 += w4.z * zv; a3 += w4.w * zv;
                a4 += w1 * zv;
            }
            float hv = tanhf(a0)
                     + tanhf(a1) * dxs[x][0]
                     + tanhf(a2) * dxs[x][1]
                     + tanhf(a3) * dxs[x][2]
                     + tanhf(a4) * dxs[x][3];
            Hc[((size_t)b * NX + x) * HID + o0 + ol] = hv;
            __syncthreads();
        }
        gbar();

        // ---- P2b: DFT + Av + update for m-tile (6 m x 128 o) ----
        {
            if (t < 6 * HID) {
                int ml = t >> 7, h = t & 127;
                vsl[ml][h] = vcur[((size_t)b * MODES + m0 + ml) * HID + h];
            }
            __syncthreads();
            if (t < 768) {
                int o = t & 127, ml = t >> 7;
                int m = m0 + ml;
                // DFT over x: Hc coalesced (256B/wave), trig broadcast
                const float* hp = Hc + (size_t)b * NX * HID + o;
                const float2* trow = T2m + (size_t)m * NX;
                float fre = 0.f, fim = 0.f;
                #pragma unroll 4
                for (int x = 0; x < NX; ++x) {
                    float hv = hp[(size_t)x * HID];
                    float2 cs = trow[x];
                    fre += hv * cs.x;
                    fim -= hv * cs.y;
                }
                // Av over h: At2 coalesced (512B/wave), v broadcast from LDS
                const float2* a2p = At2 + ((size_t)m * HID) * HID + o;
                float are = 0.f, aim = 0.f;
                #pragma unroll 4
                for (int h = 0; h < HID; ++h) {
                    float2 a = a2p[(size_t)h * HID];
                    float2 vv = vsl[ml][h];
                    are += a.x * vv.x - a.y * vv.y;
                    aim += a.y * vv.x - a.x * vv.y;
                }
                float2 vo = vsl[ml][o];
                vnxt[((size_t)b * MODES + m) * HID + o] =
                    make_float2(vo.x + are + fre, vo.y + aim + fim);
            }
            __syncthreads();
        }
        gbar();

        float2* tmp = vcur; vcur = vnxt; vnxt = tmp;
    }

    // ---- final flush: columns 48..63 (per-thread own data, no sync needed) ----
    {
        int xl = t >> 7, h = t & 127;
        int x = xg0 + xl;
        float vals[16];
        #pragma unroll
        for (int tt = 0; tt < 16; ++tt)
            vals[tt] = zbuf[(size_t)tt * ZSZ + ((size_t)b * NX + x) * HID + h];
        float* dst = out + (((size_t)b * HID + h) * NX + x) * NT + 48;
        #pragma unroll
        for (int q = 0; q < 4; ++q)
            ((float4*)dst)[q] = make_float4(vals[q*4], vals[q*4+1],
                                            vals[q*4+2], vals[q*4+3]);
    }
}

// ---------------------------------------------------------------------------
extern "C" void kernel_launch(void* const* d_in, const int* in_sizes, int n_in,
                              void* d_out, int out_size, void* d_ws, size_t ws_size,
                              hipStream_t stream) {
    const float* z0 = (const float*)d_in[0];
    const float* xi = (const float*)d_in[1];
    const float* A  = (const float*)d_in[2];
    const float* WF = (const float*)d_in[3];
    const float* WG = (const float*)d_in[4];
    float* out = (float*)d_out;

    float* ws = (float*)d_ws;
    size_t off = 0;
    auto alloc = [&](size_t n) { float* p = ws + off; off += n; return p; };

    float*  Ct   = alloc((size_t)MODES * NX);
    float*  St   = alloc((size_t)MODES * NX);
    float2* T2m  = (float2*)alloc((size_t)MODES * NX * 2);
    float4* Wt4  = (float4*)alloc((size_t)16 * HID * 8 * 4);
    float*  Wt1  = alloc((size_t)16 * HID * 8);
    float2* At2  = (float2*)alloc((size_t)MODES * HID * HID * 2);
    float2* va   = (float2*)alloc((size_t)BATCH * MODES * HID * 2);
    float2* vb   = (float2*)alloc((size_t)BATCH * MODES * HID * 2);
    float*  Hcb  = alloc((size_t)BATCH * NX * HID);
    float*  dxib = alloc((size_t)(NT - 1) * BATCH * NX * NF);
    float*  zbuf = alloc(16 * ZSZ);
    int*    barc = (int*)alloc(BATCH * 64);

    hipMemsetAsync(barc, 0, BATCH * 64 * sizeof(int), stream);
    k_tables<<<MODES, 128, 0, stream>>>(Ct, St, T2m);
    {
        int total = (NT - 1) * BATCH * NX * NF;
        k_dxi<<<(total + 255) / 256, 256, 0, stream>>>(xi, dxib);
    }
    k_wt4<<<64, 256, 0, stream>>>(WF, WG, Wt4, Wt1);
    k_at2<<<dim3(4, 4, MODES), dim3(32, 8), 0, stream>>>(A, At2);

    k_solve<<<NWG, TPB, 0, stream>>>(z0, Ct, St, T2m, Wt4, Wt1, At2, dxib,
                                     va, vb, zbuf, Hcb, out, barc);
}